// Round 1
// 439.659 us; speedup vs baseline: 1.0715x; 1.0715x over previous
//
#include <hip/hip_runtime.h>
#include <hip/hip_fp16.h>
#include <stdint.h>

#define IN    4096
#define OUT   4096
#define BATCH 8192
#define TK    64
#define BT    8     // batch rows per block in the spmm kernel

// ---------------------------------------------------------------------------
// Kernel 1: ONE WAVE PER ROW top-K.
//  - 64 keys/lane held in registers (4096/wave), 32-step MSB-greedy binary
//    search with wave-local shfl_xor reduction: no block barriers in search.
//  - selection (>T, then ==T fill) via per-wave LDS atomics.
//  - emission positions are bank-quad scheduled: position k gets an index with
//    idx&7 == (row+k)&7 where possible, so spmm's step-k gather spreads the
//    64 lanes evenly over the 8 LDS bank quads (ds_read_b128 conflict-free).
//    The assignment is an exact bijection: per-quad rank r<8 -> its residue
//    class; overflow items (r>=8) fill the free slots of deficit classes.
// ---------------------------------------------------------------------------
__global__ __launch_bounds__(256)
void topk_build_kernel(const float* __restrict__ pre_w,
                       const float* __restrict__ sign_m,
                       int2* __restrict__ wt) {
  __shared__ int selbuf[4][TK];
  __shared__ int cnt_gt[4], cnt_tie[4];

  const int wid  = threadIdx.x >> 6;
  const int lane = threadIdx.x & 63;
  const int row  = blockIdx.x * 4 + wid;
  const float* pw = pre_w + (size_t)row * IN;

  if (lane == 0) { cnt_gt[wid] = 0; cnt_tie[wid] = 0; }

  // load 64 keys per lane; keys[j*4+c] <-> global index j*256 + lane*4 + c
  uint32_t keys[64];
  #pragma unroll
  for (int j = 0; j < 16; ++j) {
    const float4 v = *(const float4*)(pw + j * 256 + lane * 4);
    const uint32_t u0 = __float_as_uint(v.x);
    const uint32_t u1 = __float_as_uint(v.y);
    const uint32_t u2 = __float_as_uint(v.z);
    const uint32_t u3 = __float_as_uint(v.w);
    keys[j * 4 + 0] = (u0 & 0x80000000u) ? ~u0 : (u0 | 0x80000000u);
    keys[j * 4 + 1] = (u1 & 0x80000000u) ? ~u1 : (u1 | 0x80000000u);
    keys[j * 4 + 2] = (u2 & 0x80000000u) ? ~u2 : (u2 | 0x80000000u);
    keys[j * 4 + 3] = (u3 & 0x80000000u) ? ~u3 : (u3 | 0x80000000u);
  }

  // MSB-greedy search for largest T with count(key >= T) >= TK. Wave-local.
  uint32_t cur = 0u;
  for (int b = 31; b >= 0; --b) {
    const uint32_t cand = cur | (1u << b);
    int c = 0;
    #pragma unroll
    for (int i = 0; i < 64; ++i) c += (keys[i] >= cand) ? 1 : 0;
    #pragma unroll
    for (int off = 32; off > 0; off >>= 1) c += __shfl_xor(c, off, 64);
    if (c >= TK) cur = cand;
  }

  __syncthreads();   // counters init visible; all waves uniform

  // strictly-greater first (count < TK guaranteed), then fill with ties
  #pragma unroll
  for (int i = 0; i < 64; ++i) {
    if (keys[i] > cur) {
      const int p = atomicAdd(&cnt_gt[wid], 1);
      selbuf[wid][p] = (i >> 2) * 256 + lane * 4 + (i & 3);
    }
  }
  __syncthreads();
  const int ng = cnt_gt[wid];
  #pragma unroll
  for (int i = 0; i < 64; ++i) {
    if (keys[i] == cur) {
      const int p = atomicAdd(&cnt_tie[wid], 1);
      if (ng + p < TK) selbuf[wid][ng + p] = (i >> 2) * 256 + lane * 4 + (i & 3);
    }
  }
  __syncthreads();

  // ---- bank-quad position assignment (all-register, ballot-based) ----
  const int myidx = selbuf[wid][lane];   // exactly TK=64 entries = 64 lanes
  const int q = myidx & 7;               // LDS bank quad of this index

  uint64_t mymask = 0ull;
  int cq[8];                             // per-quad counts (const-indexed only)
  #pragma unroll
  for (int j = 0; j < 8; ++j) {
    const uint64_t m = __ballot(q == j);
    cq[j] = (int)__popcll(m);
    if (q == j) mymask = m;
  }
  const int r = (int)__popcll(mymask & ((1ull << lane) - 1ull));  // rank in quad

  int pos;
  if (r < 8) {
    // residue class of quad q: positions k with (row+k)&7 == q
    pos = ((q - row) & 7) + 8 * r;
  } else {
    // overflow: global overflow rank R, mapped onto free slots of deficit classes
    int R = r - 8;
    #pragma unroll
    for (int j = 0; j < 8; ++j) if (j < q && cq[j] > 8) R += cq[j] - 8;
    int acc = 0; pos = -1;
    #pragma unroll
    for (int cc = 0; cc < 8; ++cc) {
      int g = 0;
      #pragma unroll
      for (int j = 0; j < 8; ++j)
        if (((row + cc) & 7) == j) g = (cq[j] < 8) ? cq[j] : 8;
      const int f = 8 - g;                  // free levels in class cc
      if (pos < 0 && R < acc + f) pos = cc + 8 * (g + (R - acc));
      acc += f;
    }
  }

  const float v = expf(pw[myidx]) * sign_m[(size_t)row * IN + myidx];
  wt[(size_t)pos * OUT + row] = make_int2(myidx, __float_as_int(v));
}

// ---------------------------------------------------------------------------
// Kernel 2: sparse matmul. Block = BT batch rows x all OUT outputs.
// x tile staged in LDS as fp16 (same 16 B/row layout as before, better
// precision than bf16, and cvt+fma fuses to v_fma_mix_f32).
// ---------------------------------------------------------------------------
__device__ __forceinline__ uint32_t pack_f16x2(float a, float b) {
  const uint32_t lo = __half_as_ushort(__float2half(a));
  const uint32_t hi = __half_as_ushort(__float2half(b));
  return lo | (hi << 16);
}

__global__ __launch_bounds__(1024, 4)
void spmm_topk_kernel(const float* __restrict__ x,
                      const int2* __restrict__ wt,
                      float* __restrict__ out) {
  __shared__ uint16_t ldsx[IN * BT];   // 64 KB: row i at byte offset i*16

  const int tid = threadIdx.x;
  const int b0 = blockIdx.x * BT;

  // ---- stage: 8 rows of x -> LDS fp16 transposed ----
  {
    const int i4 = tid * 4;
    float c[4][BT];
    #pragma unroll
    for (int j = 0; j < BT; ++j) {
      const float4 v = *(const float4*)(x + (size_t)(b0 + j) * IN + i4);
      c[0][j] = v.x; c[1][j] = v.y; c[2][j] = v.z; c[3][j] = v.w;
    }
    #pragma unroll
    for (int rr = 0; rr < 4; ++rr) {
      uint4 pk;
      pk.x = pack_f16x2(c[rr][0], c[rr][1]);
      pk.y = pack_f16x2(c[rr][2], c[rr][3]);
      pk.z = pack_f16x2(c[rr][4], c[rr][5]);
      pk.w = pack_f16x2(c[rr][6], c[rr][7]);
      *(uint4*)(&ldsx[(i4 + rr) * BT]) = pk;
    }
  }
  __syncthreads();

  // ---- compute: each lane owns one output column per group ----
  const int wave = tid >> 6;
  const int lane = tid & 63;

  for (int g = wave; g < (OUT / 64); g += 16) {   // 4 groups per wave
    const int o = g * 64 + lane;
    float a0 = 0.f, a1 = 0.f, a2 = 0.f, a3 = 0.f;
    float a4 = 0.f, a5 = 0.f, a6 = 0.f, a7 = 0.f;
    const int2* wp = wt + o;

    #pragma unroll 4
    for (int k = 0; k < TK; ++k) {
      const int2 p = wp[(size_t)k * OUT];                 // coalesced, L2-hot
      const uint4 xv = *(const uint4*)(&ldsx[p.x * BT]);  // quad-scheduled gather
      const float val = __int_as_float(p.y);
      const __half2* hv = reinterpret_cast<const __half2*>(&xv);
      a0 = fmaf(__low2float(hv[0]),  val, a0);
      a1 = fmaf(__high2float(hv[0]), val, a1);
      a2 = fmaf(__low2float(hv[1]),  val, a2);
      a3 = fmaf(__high2float(hv[1]), val, a3);
      a4 = fmaf(__low2float(hv[2]),  val, a4);
      a5 = fmaf(__high2float(hv[2]), val, a5);
      a6 = fmaf(__low2float(hv[3]),  val, a6);
      a7 = fmaf(__high2float(hv[3]), val, a7);
    }

    float* op = out + (size_t)b0 * OUT + o;
    op[0 * OUT] = a0; op[1 * OUT] = a1; op[2 * OUT] = a2; op[3 * OUT] = a3;
    op[4 * OUT] = a4; op[5 * OUT] = a5; op[6 * OUT] = a6; op[7 * OUT] = a7;
  }
}

// ---------------------------------------------------------------------------
extern "C" void kernel_launch(void* const* d_in, const int* in_sizes, int n_in,
                              void* d_out, int out_size, void* d_ws, size_t ws_size,
                              hipStream_t stream) {
  const float* x      = (const float*)d_in[0];
  const float* pre_w  = (const float*)d_in[1];
  const float* sign_m = (const float*)d_in[2];
  float* out = (float*)d_out;
  int2* wt = (int2*)d_ws;   // [TK][OUT] = 2 MB scratch

  topk_build_kernel<<<OUT / 4, 256, 0, stream>>>(pre_w, sign_m, wt);
  spmm_topk_kernel<<<BATCH / BT, 1024, 0, stream>>>(x, wt, out);
}

// Round 2
// 432.468 us; speedup vs baseline: 1.0893x; 1.0166x over previous
//
#include <hip/hip_runtime.h>
#include <hip/hip_fp16.h>
#include <stdint.h>

#define IN    4096
#define OUT   4096
#define BATCH 8192
#define TK    64
#define BT    8     // batch rows per block in the spmm kernel

// ---------------------------------------------------------------------------
// Kernel 1: ONE WAVE PER ROW top-K. Barrier-free, atomic-free.
//  - 64 keys/lane in registers, 32-step MSB-greedy threshold search with
//    shfl_xor reduction.
//  - selection via ballot + popcount rank compaction (no LDS atomics).
//  - emission positions bank-quad scheduled: pos k gets idx with
//    idx&7 == (row+k)&7 where possible; level assignment rotated by row>>3
//    so overflow "defectors" spread uniformly over k (was: clustered at
//    high k -> late spmm steps fully conflicted).
//  - wt stored as int4-pairs: element [k2*OUT+o] = {idx0,val0,idx1,val1}
//    for positions 2*k2, 2*k2+1 (halves spmm's VMEM instruction count).
// ---------------------------------------------------------------------------
__global__ __launch_bounds__(256)
void topk_build_kernel(const float* __restrict__ pre_w,
                       const float* __restrict__ sign_m,
                       int2* __restrict__ wt) {
  __shared__ int selbuf[4][TK];

  const int wid  = threadIdx.x >> 6;
  const int lane = threadIdx.x & 63;
  const int row  = blockIdx.x * 4 + wid;
  const float* pw = pre_w + (size_t)row * IN;
  const uint64_t lt = (1ull << lane) - 1ull;

  // load 64 keys per lane; keys[j*4+c] <-> global index j*256 + lane*4 + c
  uint32_t keys[64];
  #pragma unroll
  for (int j = 0; j < 16; ++j) {
    const float4 v = *(const float4*)(pw + j * 256 + lane * 4);
    const uint32_t u0 = __float_as_uint(v.x);
    const uint32_t u1 = __float_as_uint(v.y);
    const uint32_t u2 = __float_as_uint(v.z);
    const uint32_t u3 = __float_as_uint(v.w);
    keys[j * 4 + 0] = (u0 & 0x80000000u) ? ~u0 : (u0 | 0x80000000u);
    keys[j * 4 + 1] = (u1 & 0x80000000u) ? ~u1 : (u1 | 0x80000000u);
    keys[j * 4 + 2] = (u2 & 0x80000000u) ? ~u2 : (u2 | 0x80000000u);
    keys[j * 4 + 3] = (u3 & 0x80000000u) ? ~u3 : (u3 | 0x80000000u);
  }

  // MSB-greedy search for largest T with count(key >= T) >= TK. Wave-local.
  uint32_t cur = 0u;
  for (int b = 31; b >= 0; --b) {
    const uint32_t cand = cur | (1u << b);
    int c = 0;
    #pragma unroll
    for (int i = 0; i < 64; ++i) c += (keys[i] >= cand) ? 1 : 0;
    #pragma unroll
    for (int off = 32; off > 0; off >>= 1) c += __shfl_xor(c, off, 64);
    if (c >= TK) cur = cand;
  }

  // ballot-rank compaction: strictly-greater first, then ties up to TK
  int ng = 0;
  #pragma unroll
  for (int i = 0; i < 64; ++i) {
    const bool hit = keys[i] > cur;
    const uint64_t m = __ballot(hit);
    if (hit) selbuf[wid][ng + (int)__popcll(m & lt)] = (i >> 2) * 256 + lane * 4 + (i & 3);
    ng += (int)__popcll(m);
  }
  #pragma unroll
  for (int i = 0; i < 64; ++i) {
    const bool hit = keys[i] == cur;
    const uint64_t m = __ballot(hit);
    if (hit) {
      const int p = ng + (int)__popcll(m & lt);
      if (p < TK) selbuf[wid][p] = (i >> 2) * 256 + lane * 4 + (i & 3);
    }
    ng += (int)__popcll(m);
  }
  __syncthreads();   // cheap single barrier: selbuf visibility across lanes

  // ---- bank-quad position assignment (ballot-based, rotated levels) ----
  const int myidx = selbuf[wid][lane];   // exactly TK=64 entries = 64 lanes
  const int q = myidx & 7;               // LDS bank quad of this index
  const int s = (row >> 3) & 7;          // per-row level rotation

  uint64_t mymask = 0ull;
  int cq[8];
  #pragma unroll
  for (int j = 0; j < 8; ++j) {
    const uint64_t m = __ballot(q == j);
    cq[j] = (int)__popcll(m);
    if (q == j) mymask = m;
  }
  const int r = (int)__popcll(mymask & lt);  // rank within quad class

  int pos;
  if (r < 8) {
    // residue class of quad q: positions k with (row+k)&7 == q; rotated level
    pos = ((q - row) & 7) + 8 * ((r + s) & 7);
  } else {
    // overflow: global overflow rank R -> free slots of deficit classes
    int R = r - 8;
    #pragma unroll
    for (int j = 0; j < 8; ++j) if (j < q && cq[j] > 8) R += cq[j] - 8;
    int acc = 0; pos = -1;
    #pragma unroll
    for (int cc = 0; cc < 8; ++cc) {
      int g = 0;
      #pragma unroll
      for (int j = 0; j < 8; ++j)
        if (((row + cc) & 7) == j) g = (cq[j] < 8) ? cq[j] : 8;
      const int f = 8 - g;                  // free levels in class cc
      if (pos < 0 && R < acc + f) pos = cc + 8 * ((g + (R - acc) + s) & 7);
      acc += f;
    }
  }

  const float v = expf(pw[myidx]) * sign_m[(size_t)row * IN + myidx];
  // paired layout: int4 element [ (pos>>1)*OUT + row ], half pos&1
  int2* dst = wt + (((size_t)(pos >> 1) * OUT + row) * 2 + (pos & 1));
  *dst = make_int2(myidx, __float_as_int(v));
}

// ---------------------------------------------------------------------------
// Kernel 2: sparse matmul. Block = BT batch rows x all OUT outputs.
// x staged in LDS fp16 transposed (row i = 8 batch vals = 16 B).
// Per k: ds_read_b128 gather + 8x v_fma_mix_f32 (fp16 source folded into
// fp32 FMA -- halves VALU vs cvt+fma). wt loaded as int4 (2 k per load),
// software-pipelined one group (4 k) ahead in registers.
// ---------------------------------------------------------------------------
__device__ __forceinline__ uint32_t pack_f16x2(float a, float b) {
  const uint32_t lo = __half_as_ushort(__float2half(a));
  const uint32_t hi = __half_as_ushort(__float2half(b));
  return lo | (hi << 16);
}

#define FMA8(XV, VAL)                                                                                        \
  asm("v_fma_mix_f32 %0, %1, %2, %0 op_sel:[0,0,0] op_sel_hi:[1,0,0]" : "+v"(a0) : "v"((XV).x), "v"(VAL));   \
  asm("v_fma_mix_f32 %0, %1, %2, %0 op_sel:[1,0,0] op_sel_hi:[1,0,0]" : "+v"(a1) : "v"((XV).x), "v"(VAL));   \
  asm("v_fma_mix_f32 %0, %1, %2, %0 op_sel:[0,0,0] op_sel_hi:[1,0,0]" : "+v"(a2) : "v"((XV).y), "v"(VAL));   \
  asm("v_fma_mix_f32 %0, %1, %2, %0 op_sel:[1,0,0] op_sel_hi:[1,0,0]" : "+v"(a3) : "v"((XV).y), "v"(VAL));   \
  asm("v_fma_mix_f32 %0, %1, %2, %0 op_sel:[0,0,0] op_sel_hi:[1,0,0]" : "+v"(a4) : "v"((XV).z), "v"(VAL));   \
  asm("v_fma_mix_f32 %0, %1, %2, %0 op_sel:[1,0,0] op_sel_hi:[1,0,0]" : "+v"(a5) : "v"((XV).z), "v"(VAL));   \
  asm("v_fma_mix_f32 %0, %1, %2, %0 op_sel:[0,0,0] op_sel_hi:[1,0,0]" : "+v"(a6) : "v"((XV).w), "v"(VAL));   \
  asm("v_fma_mix_f32 %0, %1, %2, %0 op_sel:[1,0,0] op_sel_hi:[1,0,0]" : "+v"(a7) : "v"((XV).w), "v"(VAL));

__global__ __launch_bounds__(1024, 8)   // cap VGPR<=64: keep 2 blocks (32 waves)/CU
void spmm_topk_kernel(const float* __restrict__ x,
                      const int4* __restrict__ wt4,
                      float* __restrict__ out) {
  __shared__ uint16_t ldsx[IN * BT];   // 64 KB: row i at byte offset i*16

  const int tid = threadIdx.x;
  const int b0 = blockIdx.x * BT;

  // ---- stage: 8 rows of x -> LDS fp16 transposed ----
  {
    const int i4 = tid * 4;
    float c[4][BT];
    #pragma unroll
    for (int j = 0; j < BT; ++j) {
      const float4 v = *(const float4*)(x + (size_t)(b0 + j) * IN + i4);
      c[0][j] = v.x; c[1][j] = v.y; c[2][j] = v.z; c[3][j] = v.w;
    }
    #pragma unroll
    for (int rr = 0; rr < 4; ++rr) {
      uint4 pk;
      pk.x = pack_f16x2(c[rr][0], c[rr][1]);
      pk.y = pack_f16x2(c[rr][2], c[rr][3]);
      pk.z = pack_f16x2(c[rr][4], c[rr][5]);
      pk.w = pack_f16x2(c[rr][6], c[rr][7]);
      *(uint4*)(&ldsx[(i4 + rr) * BT]) = pk;
    }
  }
  __syncthreads();

  const int wave = tid >> 6;
  const int lane = tid & 63;

  for (int g = wave; g < (OUT / 64); g += 16) {   // 4 groups per wave
    const int o = g * 64 + lane;
    const int4* wq = wt4 + o;                     // element k2 at wq[k2*OUT]
    int4 p0 = wq[0];
    int4 p1 = wq[OUT];
    float a0 = 0.f, a1 = 0.f, a2 = 0.f, a3 = 0.f;
    float a4 = 0.f, a5 = 0.f, a6 = 0.f, a7 = 0.f;

    #pragma unroll
    for (int k2 = 0; k2 < (TK / 2); k2 += 2) {    // 4 k-entries per iter
      int4 n0, n1;
      if (k2 + 2 < (TK / 2)) {                    // prefetch next group
        n0 = wq[2 * OUT];
        n1 = wq[3 * OUT];
      }
      const uint4 x0 = *(const uint4*)(&ldsx[p0.x * BT]);
      const uint4 x1 = *(const uint4*)(&ldsx[p0.z * BT]);
      const uint4 x2 = *(const uint4*)(&ldsx[p1.x * BT]);
      const uint4 x3 = *(const uint4*)(&ldsx[p1.z * BT]);
      const float v0 = __int_as_float(p0.y);
      const float v1 = __int_as_float(p0.w);
      const float v2 = __int_as_float(p1.y);
      const float v3 = __int_as_float(p1.w);
      FMA8(x0, v0)
      FMA8(x1, v1)
      FMA8(x2, v2)
      FMA8(x3, v3)
      if (k2 + 2 < (TK / 2)) { p0 = n0; p1 = n1; wq += 2 * OUT; }
    }

    float* op = out + (size_t)b0 * OUT + o;
    op[0 * OUT] = a0; op[1 * OUT] = a1; op[2 * OUT] = a2; op[3 * OUT] = a3;
    op[4 * OUT] = a4; op[5 * OUT] = a5; op[6 * OUT] = a6; op[7 * OUT] = a7;
  }
}

// ---------------------------------------------------------------------------
extern "C" void kernel_launch(void* const* d_in, const int* in_sizes, int n_in,
                              void* d_out, int out_size, void* d_ws, size_t ws_size,
                              hipStream_t stream) {
  const float* x      = (const float*)d_in[0];
  const float* pre_w  = (const float*)d_in[1];
  const float* sign_m = (const float*)d_in[2];
  float* out = (float*)d_out;

  topk_build_kernel<<<OUT / 4, 256, 0, stream>>>(pre_w, sign_m, (int2*)d_ws);
  spmm_topk_kernel<<<BATCH / BT, 1024, 0, stream>>>(x, (const int4*)d_ws, out);
}